// Round 6
// baseline (382.417 us; speedup 1.0000x reference)
//
#include <hip/hip_runtime.h>
#include <hip/hip_bf16.h>

#define D 128
#define EPS 1e-5f

typedef __attribute__((ext_vector_type(8))) short short8;
typedef __attribute__((ext_vector_type(4))) float float4v;

__device__ inline ushort f2bf(float f) {
    __hip_bfloat16 b = __float2bfloat16(f);
    return *reinterpret_cast<ushort*>(&b);
}
__device__ inline float bf_lo(uint u) { return __uint_as_float(u << 16); }
__device__ inline float bf_hi(uint u) { return __uint_as_float(u & 0xffff0000u); }

// ---------- K1: LN1 + ReLU, fp32 in -> bf16 out. One wave per node. ----------
__global__ void k_ln1(const float* __restrict__ x, const int* __restrict__ ntp,
                      const float* __restrict__ gamma, const float* __restrict__ beta,
                      ushort* __restrict__ y, int N) {
    int n = blockIdx.x * 4 + (threadIdx.x >> 6);
    if (n >= N) return;
    int l = threadIdx.x & 63;
    float2 v = *(const float2*)(x + (size_t)n * D + 2 * l);
    float s = v.x + v.y, s2 = v.x * v.x + v.y * v.y;
    #pragma unroll
    for (int o = 32; o; o >>= 1) { s += __shfl_xor(s, o, 64); s2 += __shfl_xor(s2, o, 64); }
    float mu = s * (1.0f / D);
    float var = s2 * (1.0f / D) - mu * mu;
    float inv = rsqrtf(var + EPS);
    int t = ntp[n];
    float2 g = *(const float2*)(gamma + t * D + 2 * l);
    float2 b = *(const float2*)(beta + t * D + 2 * l);
    float a0 = fmaxf((v.x - mu) * inv * g.x + b.x, 0.0f);
    float a1 = fmaxf((v.y - mu) * inv * g.y + b.y, 0.0f);
    ((uint*)(y + (size_t)n * D))[l] = ((uint)f2bf(a1) << 16) | f2bf(a0);
}

// ---------- K2: weights -> bf16 in MFMA B-FRAGMENT order ----------------------
// m==0: W_root, 1..8: W_rel[m-1], 9..12: W_mlp[m-9].
__global__ void k_cvt(const float* __restrict__ Wrel, const float* __restrict__ Wroot,
                      const float* __restrict__ Wmlp, ushort* __restrict__ Wt) {
    __shared__ ushort t[128][136];
    int m = blockIdx.x;
    const float* src = (m == 0) ? Wroot
                     : (m <= 8) ? Wrel + (size_t)(m - 1) * D * D
                                : Wmlp + (size_t)(m - 9) * D * D;
    for (int i = threadIdx.x; i < D * D; i += 256) {
        int k = i >> 7, n = i & 127;
        t[n][k] = f2bf(src[i]);
    }
    __syncthreads();
    ushort* dst = Wt + (size_t)m * D * D;
    for (int i = threadIdx.x; i < D * D; i += 256) {
        int frag = i >> 9;            // 0..31  (nt*4+ks)
        int lane = (i >> 3) & 63;
        int j = i & 7;
        int nt = frag >> 2, ks = frag & 3;
        int n = nt * 16 + (lane & 15);
        int k = ks * 32 + (lane >> 4) * 8 + j;
        dst[i] = t[n][k];
    }
}

// ---------- edge bucketing by (dst*8+type): hist, 2-level scan, scatter -------
__global__ void k_ehist(const int* __restrict__ edst, const int* __restrict__ etyp,
                        int* __restrict__ hist, int E) {
    int e = blockIdx.x * blockDim.x + threadIdx.x;
    if (e < E) atomicAdd(&hist[edst[e] * 8 + etyp[e]], 1);
}
__global__ void k_scan1(const int* __restrict__ hist, int* __restrict__ blocksum, int M) {
    __shared__ int ps[256];
    int t = threadIdx.x;
    int base = blockIdx.x * 1024 + t * 4;
    int s = 0;
    #pragma unroll
    for (int k = 0; k < 4; ++k) { int i = base + k; if (i < M) s += hist[i]; }
    ps[t] = s;
    __syncthreads();
    if (t == 0) {
        int tot = 0;
        for (int i = 0; i < 256; ++i) tot += ps[i];
        blocksum[blockIdx.x] = tot;
    }
}
__global__ void k_scan2(int* __restrict__ blocksum, int* __restrict__ offs, int B, int M) {
    if (threadIdx.x == 0) {
        int o = 0;
        for (int b = 0; b < B; ++b) { int c = blocksum[b]; blocksum[b] = o; o += c; }
        offs[M] = o;
    }
}
__global__ void k_scan3(const int* __restrict__ hist, const int* __restrict__ blockoff,
                        int* __restrict__ offs, int* __restrict__ cursor, int M) {
    __shared__ int ps[256];
    int t = threadIdx.x;
    int base = blockIdx.x * 1024 + t * 4;
    int s = 0;
    #pragma unroll
    for (int k = 0; k < 4; ++k) { int i = base + k; if (i < M) s += hist[i]; }
    int mysum = s;
    ps[t] = s;
    __syncthreads();
    for (int off = 1; off < 256; off <<= 1) {
        int v = (t >= off) ? ps[t - off] : 0;
        __syncthreads();
        ps[t] += v;
        __syncthreads();
    }
    int run = ps[t] - mysum + blockoff[blockIdx.x];
    #pragma unroll
    for (int k = 0; k < 4; ++k) {
        int i = base + k;
        if (i < M) { offs[i] = run; cursor[i] = run; run += hist[i]; }
    }
}
__global__ void k_escatter(const int* __restrict__ edst, const int* __restrict__ esrc,
                           const int* __restrict__ etyp, int* __restrict__ cursor,
                           uint* __restrict__ epack, int E) {
    int e = blockIdx.x * blockDim.x + threadIdx.x;
    if (e < E) {
        int p = atomicAdd(&cursor[edst[e] * 8 + etyp[e]], 1);
        epack[p] = (uint)esrc[e];
    }
}

// ---------- K3: FUSED gather + GEMM (K=1152) + residual + LN2 + ReLU ----------
// grid ceil(N/64), block 256 (4 waves x 16 rows).
// Per mat: stage W in LDS (frag order); mats 1..8 also gather z into zlds
// (4 threads/node x 32 cols, fp32 reg accum -> bf16 LDS); then 32 MFMAs/wave.
#define ZSTR 136   // zlds row stride in ushorts (272 B: 16B-aligned, 2-way banks)
__launch_bounds__(256)
__global__ void k_zgemm(const ushort* __restrict__ ybuf, const ushort* __restrict__ Wt,
                        const uint* __restrict__ epack, const int* __restrict__ offs2,
                        const float* __restrict__ x, const int* __restrict__ ntp,
                        const float* __restrict__ gamma, const float* __restrict__ beta,
                        float* __restrict__ x2, ushort* __restrict__ y2, int N) {
    __shared__ ushort wlds[16384];          // 32 KB: current W matrix, frag order
    __shared__ ushort zlds[64 * ZSTR];      // 17 KB: current relation's z tile
    int tid = threadIdx.x;
    int wave = tid >> 6, lane = tid & 63;
    int quad = lane >> 4, l15 = lane & 15;
    int base = blockIdx.x * 64 + wave * 16;
    int arow = min(base + l15, N - 1);
    const ushort* yrow = ybuf + (size_t)arow * 128;
    const uint* yb = (const uint*)ybuf;

    int nd = tid >> 2, q = tid & 3;         // gather role: node nd, cols [q*32,q*32+32)
    int gv = blockIdx.x * 64 + nd;

    float4v acc[8];
    #pragma unroll
    for (int nt = 0; nt < 8; ++nt) acc[nt] = (float4v){0.f, 0.f, 0.f, 0.f};

    for (int mat = 0; mat < 9; ++mat) {
        __syncthreads();                    // prior MFMA reads of wlds/zlds done
        // stage W[mat] into LDS (lane-contiguous 16B copies)
        const ushort* wsrc = Wt + (size_t)mat * 16384;
        #pragma unroll
        for (int jj = 0; jj < 8; ++jj)
            *(uint4*)(wlds + jj * 2048 + tid * 8) = *(const uint4*)(wsrc + jj * 2048 + tid * 8);
        if (mat >= 1) {
            // gather z tile for relation mat-1
            float ga[32];
            #pragma unroll
            for (int i = 0; i < 32; ++i) ga[i] = 0.f;
            if (gv < N) {
                int key = gv * 8 + (mat - 1);
                int j0 = offs2[key], j1 = offs2[key + 1];
                for (int j = j0; j < j1; ++j) {
                    uint s = epack[j];
                    const uint4* yr = (const uint4*)(yb + (size_t)s * 64 + q * 16);
                    #pragma unroll
                    for (int k = 0; k < 4; ++k) {
                        uint4 u = yr[k];
                        ga[k * 8 + 0] += bf_lo(u.x); ga[k * 8 + 1] += bf_hi(u.x);
                        ga[k * 8 + 2] += bf_lo(u.y); ga[k * 8 + 3] += bf_hi(u.y);
                        ga[k * 8 + 4] += bf_lo(u.z); ga[k * 8 + 5] += bf_hi(u.z);
                        ga[k * 8 + 6] += bf_lo(u.w); ga[k * 8 + 7] += bf_hi(u.w);
                    }
                }
            }
            uint* zr = (uint*)(zlds + nd * ZSTR + q * 32);
            #pragma unroll
            for (int i = 0; i < 16; ++i)
                zr[i] = ((uint)f2bf(ga[2 * i + 1]) << 16) | f2bf(ga[2 * i]);
        }
        __syncthreads();
        // A fragments
        short8 a[4];
        if (mat == 0) {
            #pragma unroll
            for (int ks = 0; ks < 4; ++ks)
                a[ks] = *(const short8*)(yrow + ks * 32 + quad * 8);
        } else {
            const ushort* zp = zlds + (wave * 16 + l15) * ZSTR + quad * 8;
            #pragma unroll
            for (int ks = 0; ks < 4; ++ks)
                a[ks] = *(const short8*)(zp + ks * 32);
        }
        #pragma unroll
        for (int nt = 0; nt < 8; ++nt) {
            #pragma unroll
            for (int ks = 0; ks < 4; ++ks) {
                short8 b = *(const short8*)(wlds + (((nt * 4 + ks) * 64 + lane) << 3));
                acc[nt] = __builtin_amdgcn_mfma_f32_16x16x32_bf16(a[ks], b, acc[nt], 0, 0, 0);
            }
        }
    }

    // epilogue: x2 = x + acc; LN2 + ReLU -> y2
    float s[4] = {0.f, 0.f, 0.f, 0.f}, s2[4] = {0.f, 0.f, 0.f, 0.f};
    #pragma unroll
    for (int nt = 0; nt < 8; ++nt) {
        int col = nt * 16 + l15;
        #pragma unroll
        for (int r = 0; r < 4; ++r) {
            int row = base + quad * 4 + r;
            float xv = (row < N) ? x[(size_t)row * D + col] : 0.f;
            float t = acc[nt][r] + xv;
            acc[nt][r] = t;
            s[r] += t; s2[r] += t * t;
        }
    }
    #pragma unroll
    for (int r = 0; r < 4; ++r) {
        #pragma unroll
        for (int o = 1; o < 16; o <<= 1) {
            s[r]  += __shfl_xor(s[r],  o, 64);
            s2[r] += __shfl_xor(s2[r], o, 64);
        }
    }
    #pragma unroll
    for (int r = 0; r < 4; ++r) {
        int row = base + quad * 4 + r;
        int rc = min(row, N - 1);
        int t = ntp[rc];
        float mu  = s[r] * (1.0f / D);
        float var = s2[r] * (1.0f / D) - mu * mu;
        float inv = rsqrtf(var + EPS);
        #pragma unroll
        for (int nt = 0; nt < 8; ++nt) {
            int col = nt * 16 + l15;
            float xx = acc[nt][r];
            float yn = fmaxf((xx - mu) * inv * gamma[t * D + col] + beta[t * D + col], 0.f);
            if (row < N) {
                x2[(size_t)row * D + col] = xx;
                y2[(size_t)row * D + col] = f2bf(yn);
            }
        }
    }
}

// ---------- node-type bucketing (64-aligned) ----------------------------------
__global__ void k_nhist(const int* __restrict__ ntp, int* __restrict__ small, int N) {
    __shared__ int c[4];
    if (threadIdx.x < 4) c[threadIdx.x] = 0;
    __syncthreads();
    int n = blockIdx.x * blockDim.x + threadIdx.x;
    if (n < N) atomicAdd(&c[ntp[n]], 1);
    __syncthreads();
    if (threadIdx.x < 4 && c[threadIdx.x]) atomicAdd(&small[threadIdx.x], c[threadIdx.x]);
}
__global__ void k_prep(int* __restrict__ small, int gridMlp) {
    __shared__ int st[5];
    if (threadIdx.x == 0) {
        int o = 0;
        for (int t = 0; t < 4; ++t) {
            small[8 + t] = o;
            st[t] = o;
            o += (small[t] + 63) & ~63;
        }
        small[12] = o;
        st[4] = o;
    }
    __syncthreads();
    int* tob = small + 16;
    for (int b = threadIdx.x; b < gridMlp; b += blockDim.x) {
        int b64 = b * 64;
        int t = -1;
        for (int i = 0; i < 4; ++i)
            if (b64 >= st[i] && b64 < st[i + 1]) t = i;
        tob[b] = t;
    }
}
__global__ void k_nscatter(const int* __restrict__ ntp, int* __restrict__ small,
                           int* __restrict__ perm_pad, int N) {
    __shared__ int cnt[4], base[4];
    int tid = threadIdx.x;
    if (tid < 4) cnt[tid] = 0;
    __syncthreads();
    int n = blockIdx.x * blockDim.x + tid;
    int t = 0, rank = 0;
    bool valid = (n < N);
    if (valid) { t = ntp[n]; rank = atomicAdd(&cnt[t], 1); }
    __syncthreads();
    if (tid < 4) base[tid] = cnt[tid] ? atomicAdd(&small[4 + tid], cnt[tid]) : 0;
    __syncthreads();
    if (valid) perm_pad[small[8 + t] + base[t] + rank] = n;
}

// ---------- K5: MLP MFMA + residual + bias, type-uniform 64-row blocks --------
__global__ void k_mlp(const ushort* __restrict__ y2, const float* __restrict__ x2,
                      const int* __restrict__ perm_pad, const int* __restrict__ small,
                      const ushort* __restrict__ Wt, const float* __restrict__ bmlp,
                      float* __restrict__ out, int N) {
    int t = small[16 + blockIdx.x];
    if (t < 0) return;
    int wave = threadIdx.x >> 6;
    int lane = threadIdx.x & 63;
    int quad = lane >> 4;
    int base = blockIdx.x * 64 + wave * 16;
    int node = perm_pad[base + (lane & 15)];
    int arow = node < 0 ? 0 : node;
    short8 a[4];
    const ushort* yrow = y2 + (size_t)arow * D + quad * 8;
    #pragma unroll
    for (int ks = 0; ks < 4; ++ks) a[ks] = *(const short8*)(yrow + ks * 32);
    int srow[4];
    #pragma unroll
    for (int r = 0; r < 4; ++r) srow[r] = perm_pad[base + quad * 4 + r];
    const ushort* Wb = Wt + (size_t)(9 + t) * D * D;
    #pragma unroll
    for (int nt = 0; nt < 8; ++nt) {
        float4v acc = {0.f, 0.f, 0.f, 0.f};
        #pragma unroll
        for (int ks = 0; ks < 4; ++ks) {
            short8 b = *(const short8*)(Wb + (((nt * 4 + ks) * 64 + lane) << 3));
            acc = __builtin_amdgcn_mfma_f32_16x16x32_bf16(a[ks], b, acc, 0, 0, 0);
        }
        int col = nt * 16 + (lane & 15);
        float bm = bmlp[t * D + col];
        #pragma unroll
        for (int r = 0; r < 4; ++r) {
            if (srow[r] >= 0)
                out[(size_t)srow[r] * D + col] =
                    x2[(size_t)srow[r] * D + col] + acc[r] + bm;
        }
    }
}

// ---------- launch ------------------------------------------------------------
extern "C" void kernel_launch(void* const* d_in, const int* in_sizes, int n_in,
                              void* d_out, int out_size, void* d_ws, size_t ws_size,
                              hipStream_t stream) {
    const float* x          = (const float*)d_in[0];
    const int*   esrc       = (const int*)d_in[1];
    const int*   edst       = (const int*)d_in[2];
    const int*   ntyp       = (const int*)d_in[3];
    const int*   etyp       = (const int*)d_in[4];
    const float* conv_gamma = (const float*)d_in[5];
    const float* conv_beta  = (const float*)d_in[6];
    const float* W_rel      = (const float*)d_in[7];
    const float* W_root     = (const float*)d_in[8];
    const float* mlp_gamma  = (const float*)d_in[9];
    const float* mlp_beta   = (const float*)d_in[10];
    const float* W_mlp      = (const float*)d_in[11];
    const float* b_mlp      = (const float*)d_in[12];
    float* out = (float*)d_out;

    int N = in_sizes[0] / D;
    int E = in_sizes[1];
    int M = N * 8;                          // (dst,type) key space
    int gridMlp = (N + 252 + 63) / 64;
    int scanB = (M + 1023) / 1024;

    char* p = (char*)d_ws;
    auto take = [&p](size_t bytes) { char* q = p; p += (bytes + 255) & ~(size_t)255; return q; };
    ushort* ybuf   = (ushort*)take((size_t)N * D * 2);
    ushort* y2     = (ushort*)take((size_t)N * D * 2);
    float*  x2     = (float*)take((size_t)N * D * 4);
    ushort* Wt     = (ushort*)take((size_t)13 * D * D * 2);
    int*    hist   = (int*)take((size_t)M * 4);
    int*    offs   = (int*)take((size_t)(M + 1) * 4);
    int*    cursor = (int*)take((size_t)M * 4);
    uint*   epack  = (uint*)take((size_t)E * 4);
    int*    permpad= (int*)take((size_t)(N + 256) * 4);
    int*    small  = (int*)take((size_t)(16 + gridMlp) * 4);
    int*    bsum   = (int*)take((size_t)scanB * 4);

    hipMemsetAsync(hist, 0, (size_t)M * 4, stream);
    hipMemsetAsync(small, 0, 16 * 4, stream);
    hipMemsetAsync(permpad, 0xFF, (size_t)(N + 256) * 4, stream);

    k_ln1<<<(N + 3) / 4, 256, 0, stream>>>(x, ntyp, conv_gamma, conv_beta, ybuf, N);
    k_cvt<<<13, 256, 0, stream>>>(W_rel, W_root, W_mlp, Wt);

    k_ehist<<<(E + 255) / 256, 256, 0, stream>>>(edst, etyp, hist, E);
    k_scan1<<<scanB, 256, 0, stream>>>(hist, bsum, M);
    k_scan2<<<1, 64, 0, stream>>>(bsum, offs, scanB, M);
    k_scan3<<<scanB, 256, 0, stream>>>(hist, bsum, offs, cursor, M);
    k_escatter<<<(E + 255) / 256, 256, 0, stream>>>(edst, esrc, etyp, cursor, epack, E);

    k_nhist<<<(N + 255) / 256, 256, 0, stream>>>(ntyp, small, N);
    k_prep<<<1, 256, 0, stream>>>(small, gridMlp);
    k_nscatter<<<(N + 255) / 256, 256, 0, stream>>>(ntyp, small, permpad, N);

    k_zgemm<<<(N + 63) / 64, 256, 0, stream>>>(ybuf, Wt, epack, offs, x, ntyp,
                                               mlp_gamma, mlp_beta, x2, y2, N);

    k_mlp<<<gridMlp, 256, 0, stream>>>(y2, x2, permpad, small, Wt, b_mlp, out, N);
}